// Round 1
// baseline (13007.846 us; speedup 1.0000x reference)
//
#include <hip/hip_runtime.h>

#define B_ 64
#define S_ 512
#define I_ 512
#define H_ 1024
#define NBLK 128
#define OFF_H 33554432            // B_*S_*H_
#define OFF_C (33554432 + 65536)  // + B_*H_

typedef short bf16x8 __attribute__((ext_vector_type(8)));
typedef unsigned short u16x8 __attribute__((ext_vector_type(8)));
typedef float f32x4 __attribute__((ext_vector_type(4)));

__device__ __forceinline__ unsigned short f2b(float f) {
  unsigned u = __float_as_uint(f);
  u += 0x7fffu + ((u >> 16) & 1u);   // RNE
  return (unsigned short)(u >> 16);
}
__device__ __forceinline__ float sigf(float x) { return 1.0f / (1.0f + __expf(-x)); }
__device__ __forceinline__ float tanh_(float x) { return 2.0f / (1.0f + __expf(-2.0f * x)) - 1.0f; }

// ---------- preamble: x -> bf16 ----------
__global__ __launch_bounds__(256) void k_cvt_x(const float* __restrict__ x,
                                               unsigned short* __restrict__ x16) {
  long long i = ((long long)blockIdx.x * 256 + threadIdx.x) * 8;
  float4 a = *(const float4*)(x + i);
  float4 b = *(const float4*)(x + i + 4);
  u16x8 o;
  o[0] = f2b(a.x); o[1] = f2b(a.y); o[2] = f2b(a.z); o[3] = f2b(a.w);
  o[4] = f2b(b.x); o[5] = f2b(b.y); o[6] = f2b(b.z); o[7] = f2b(b.w);
  *(u16x8*)(x16 + i) = o;
}

// ---------- preamble: W_x -> fragment-ordered bf16 [g][ct2][kc16][lane][8] ----------
__global__ __launch_bounds__(256) void k_wx(const float* __restrict__ Wx,
                                            unsigned short* __restrict__ wxf) {
  int gid = blockIdx.x * 256 + threadIdx.x;
  int lane = gid & 63, kc = (gid >> 6) & 15, ct = (gid >> 10) & 1, g = gid >> 11;
  int c = lane & 15, q = lane >> 4;
  int col = (ct * 2 + (c >> 3)) * H_ + g * 8 + (c & 7);  // gate-major column mapping
  int k0 = kc * 32 + q * 8;
  u16x8 o;
#pragma unroll
  for (int j = 0; j < 8; ++j) o[j] = f2b(Wx[(long long)(k0 + j) * (4 * H_) + col]);
  *(u16x8*)(wxf + (long long)gid * 8) = o;
}

// ---------- preamble: W_h -> fragment-ordered bf16 [g][ct2][kc32][lane][8] ----------
__global__ __launch_bounds__(256) void k_wh(const float* __restrict__ Wh,
                                            unsigned short* __restrict__ whf) {
  int gid = blockIdx.x * 256 + threadIdx.x;
  int lane = gid & 63, kc = (gid >> 6) & 31, ct = (gid >> 11) & 1, g = gid >> 12;
  int c = lane & 15, q = lane >> 4;
  int col = (ct * 2 + (c >> 3)) * H_ + g * 8 + (c & 7);
  int k0 = kc * 32 + q * 8;
  u16x8 o;
#pragma unroll
  for (int j = 0; j < 8; ++j) o[j] = f2b(Wh[(long long)(k0 + j) * (4 * H_) + col]);
  *(u16x8*)(whf + (long long)gid * 8) = o;
}

// ---------- persistent scan kernel: 128 blocks x 256 threads ----------
__global__ __launch_bounds__(256, 1) void k_scan(
    const unsigned short* __restrict__ x16, const unsigned short* __restrict__ wxf,
    const unsigned short* __restrict__ whf, const float* __restrict__ bias,
    unsigned short* __restrict__ hbuf, unsigned* __restrict__ cnt,
    float* __restrict__ out) {
  __shared__ unsigned short ldsWh[2 * 32 * 64 * 8];  // 64 KB, fragment order
  __shared__ unsigned short ldsWx[2 * 16 * 64 * 8];  // 32 KB, fragment order
  const int tid = threadIdx.x, g = blockIdx.x;

  for (int i = tid; i < 4096; i += 256)
    ((u16x8*)ldsWh)[i] = ((const u16x8*)(whf + (long long)g * 32768))[i];
  for (int i = tid; i < 2048; i += 256)
    ((u16x8*)ldsWx)[i] = ((const u16x8*)(wxf + (long long)g * 16384))[i];
  __syncthreads();

  const int wave = tid >> 6, lane = tid & 63;
  const int c = lane & 15, q = lane >> 4;
  const int rowA = wave * 16 + c;   // A-operand batch row
  const int kofs = q * 8;
  const int j = 8 * g + (c & 7);    // hidden index owned (lanes c<8)
  const float bias0 = bias[(c >> 3) * H_ + j];        // i (c<8) / f (c>=8)
  const float bias1 = bias[(2 + (c >> 3)) * H_ + j];  // g / o
  const int rowD = wave * 16 + q * 4;
  f32x4 cst = {0.f, 0.f, 0.f, 0.f};

  const unsigned short* xrow = x16 + (long long)rowA * (S_ * I_) + kofs;
  const unsigned short* hrowA = hbuf + rowA * H_ + kofs;

  for (int t = 0; t < S_; ++t) {
    f32x4 a0 = {bias0, bias0, bias0, bias0};
    f32x4 a1 = {bias1, bias1, bias1, bias1};

    // ---- x-part: independent of h_t, overlaps barrier wait ----
    const unsigned short* xp = xrow + t * I_;
#pragma unroll
    for (int kc = 0; kc < 16; ++kc) {
      bf16x8 av = *(const bf16x8*)(xp + kc * 32);
      bf16x8 b0 = *(const bf16x8*)(ldsWx + kc * 512 + lane * 8);
      bf16x8 b1 = *(const bf16x8*)(ldsWx + (16 + kc) * 512 + lane * 8);
      a0 = __builtin_amdgcn_mfma_f32_16x16x32_bf16(av, b0, a0, 0, 0, 0);
      a1 = __builtin_amdgcn_mfma_f32_16x16x32_bf16(av, b1, a1, 0, 0, 0);
    }

    // ---- wait until all blocks published h_t ----
    if (t > 0) {
      if (tid == 0) {
        unsigned target = (unsigned)NBLK * (unsigned)t;
        while (__hip_atomic_load(cnt, __ATOMIC_ACQUIRE, __HIP_MEMORY_SCOPE_AGENT) < target)
          __builtin_amdgcn_s_sleep(2);
      }
      __syncthreads();
    }

    // ---- h-part ----
    const unsigned short* hp = hrowA + (t & 1) * (B_ * H_);
#pragma unroll 8
    for (int kc = 0; kc < 32; ++kc) {
      bf16x8 av = *(const bf16x8*)(hp + kc * 32);
      bf16x8 b0 = *(const bf16x8*)(ldsWh + kc * 512 + lane * 8);
      bf16x8 b1 = *(const bf16x8*)(ldsWh + (32 + kc) * 512 + lane * 8);
      a0 = __builtin_amdgcn_mfma_f32_16x16x32_bf16(av, b0, a0, 0, 0, 0);
      a1 = __builtin_amdgcn_mfma_f32_16x16x32_bf16(av, b1, a1, 0, 0, 0);
    }

    // ---- elementwise LSTM update (lane c pairs with lane c+8) ----
    f32x4 h4;
#pragma unroll
    for (int r = 0; r < 4; ++r) {
      float fg = __shfl_xor(a0[r], 8, 64);  // f at lanes c<8
      float og = __shfl_xor(a1[r], 8, 64);  // o at lanes c<8
      float iv = sigf(a0[r]);
      float fv = sigf(fg);
      float gv = tanh_(a1[r]);
      float ov = sigf(og);
      float cv = fv * cst[r] + iv * gv;
      cst[r] = cv;
      h4[r] = ov * tanh_(cv);
    }
    if (c < 8) {
      unsigned short* hw = hbuf + ((t + 1) & 1) * (B_ * H_);
#pragma unroll
      for (int r = 0; r < 4; ++r) {
        int b = rowD + r;
        hw[b * H_ + j] = f2b(h4[r]);
        out[((long long)b * S_ + t) * H_ + j] = h4[r];
      }
      if (t == S_ - 1) {
#pragma unroll
        for (int r = 0; r < 4; ++r) {
          int b = rowD + r;
          out[OFF_H + b * H_ + j] = h4[r];
          out[OFF_C + b * H_ + j] = cst[r];
        }
      }
    }

    // ---- publish h_{t+1} ----
    __threadfence();
    __syncthreads();
    if (tid == 0)
      __hip_atomic_fetch_add(cnt, 1u, __ATOMIC_RELEASE, __HIP_MEMORY_SCOPE_AGENT);
  }
}

extern "C" void kernel_launch(void* const* d_in, const int* in_sizes, int n_in,
                              void* d_out, int out_size, void* d_ws, size_t ws_size,
                              hipStream_t stream) {
  const float* x = (const float*)d_in[0];
  const float* Wx = (const float*)d_in[1];
  const float* Wh = (const float*)d_in[2];
  const float* bias = (const float*)d_in[3];
  float* out = (float*)d_out;
  char* ws = (char*)d_ws;

  // ws layout (bytes):
  //   [0,4)            barrier counter
  //   [1024, 263168)   h double buffer, bf16 [2][64][1024]
  //   [263168, ..)     x16 bf16 (33.5 MB)
  //   [33817600, ..)   wxf fragment-ordered W_x bf16 (4 MB)
  //   [38011904, ..)   whf fragment-ordered W_h bf16 (8 MB)   total ~46.4 MB
  unsigned* cnt = (unsigned*)ws;
  unsigned short* hbuf = (unsigned short*)(ws + 1024);
  unsigned short* x16 = (unsigned short*)(ws + 263168);
  unsigned short* wxf = (unsigned short*)(ws + 33817600);
  unsigned short* whf = (unsigned short*)(ws + 38011904);

  hipMemsetAsync(ws, 0, 263168, stream);  // zero counter + h0
  hipLaunchKernelGGL(k_cvt_x, dim3(8192), dim3(256), 0, stream, x, x16);
  hipLaunchKernelGGL(k_wx, dim3(1024), dim3(256), 0, stream, Wx, wxf);
  hipLaunchKernelGGL(k_wh, dim3(2048), dim3(256), 0, stream, Wh, whf);
  hipLaunchKernelGGL(k_scan, dim3(NBLK), dim3(256), 0, stream, x16, wxf, whf, bias,
                     hbuf, cnt, out);
  (void)in_sizes; (void)n_in; (void)out_size; (void)ws_size;
}

// Round 2
// 6170.510 us; speedup vs baseline: 2.1081x; 2.1081x over previous
//
#include <hip/hip_runtime.h>

#define B_ 64
#define S_ 512
#define I_ 512
#define H_ 1024
#define NBLK 128
#define OFF_H 33554432            // B_*S_*H_
#define OFF_C (33554432 + 65536)  // + B_*H_

typedef short bf16x8 __attribute__((ext_vector_type(8)));
typedef unsigned short u16x8 __attribute__((ext_vector_type(8)));
typedef float f32x4 __attribute__((ext_vector_type(4)));

__device__ __forceinline__ unsigned short f2b(float f) {
  unsigned u = __float_as_uint(f);
  u += 0x7fffu + ((u >> 16) & 1u);   // RNE
  return (unsigned short)(u >> 16);
}
__device__ __forceinline__ float sigf(float x) { return 1.0f / (1.0f + __expf(-x)); }
__device__ __forceinline__ float tanh_(float x) { return 2.0f / (1.0f + __expf(-2.0f * x)) - 1.0f; }

// ---------- preamble: x -> bf16 ----------
__global__ __launch_bounds__(256) void k_cvt_x(const float* __restrict__ x,
                                               unsigned short* __restrict__ x16) {
  long long i = ((long long)blockIdx.x * 256 + threadIdx.x) * 8;
  float4 a = *(const float4*)(x + i);
  float4 b = *(const float4*)(x + i + 4);
  u16x8 o;
  o[0] = f2b(a.x); o[1] = f2b(a.y); o[2] = f2b(a.z); o[3] = f2b(a.w);
  o[4] = f2b(b.x); o[5] = f2b(b.y); o[6] = f2b(b.z); o[7] = f2b(b.w);
  *(u16x8*)(x16 + i) = o;
}

// ---------- preamble: W_x -> fragment-ordered bf16 [g][ct2][kc16][lane][8] ----------
__global__ __launch_bounds__(256) void k_wx(const float* __restrict__ Wx,
                                            unsigned short* __restrict__ wxf) {
  int gid = blockIdx.x * 256 + threadIdx.x;
  int lane = gid & 63, kc = (gid >> 6) & 15, ct = (gid >> 10) & 1, g = gid >> 11;
  int c = lane & 15, q = lane >> 4;
  int col = (ct * 2 + (c >> 3)) * H_ + g * 8 + (c & 7);  // gate-major column mapping
  int k0 = kc * 32 + q * 8;
  u16x8 o;
#pragma unroll
  for (int j = 0; j < 8; ++j) o[j] = f2b(Wx[(long long)(k0 + j) * (4 * H_) + col]);
  *(u16x8*)(wxf + (long long)gid * 8) = o;
}

// ---------- preamble: W_h -> fragment-ordered bf16 [g][ct2][kc32][lane][8] ----------
__global__ __launch_bounds__(256) void k_wh(const float* __restrict__ Wh,
                                            unsigned short* __restrict__ whf) {
  int gid = blockIdx.x * 256 + threadIdx.x;
  int lane = gid & 63, kc = (gid >> 6) & 31, ct = (gid >> 11) & 1, g = gid >> 12;
  int c = lane & 15, q = lane >> 4;
  int col = (ct * 2 + (c >> 3)) * H_ + g * 8 + (c & 7);
  int k0 = kc * 32 + q * 8;
  u16x8 o;
#pragma unroll
  for (int j = 0; j < 8; ++j) o[j] = f2b(Wh[(long long)(k0 + j) * (4 * H_) + col]);
  *(u16x8*)(whf + (long long)gid * 8) = o;
}

// ---------- persistent scan kernel: 128 blocks x 256 threads ----------
__global__ __launch_bounds__(256, 1) void k_scan(
    const unsigned short* __restrict__ x16, const unsigned short* __restrict__ wxf,
    const unsigned short* __restrict__ whf, const float* __restrict__ bias,
    unsigned short* __restrict__ hbuf, unsigned* __restrict__ flags,
    float* __restrict__ out) {
  __shared__ unsigned short ldsWh[2 * 32 * 64 * 8];  // 64 KB, fragment order
  __shared__ unsigned short ldsWx[2 * 16 * 64 * 8];  // 32 KB, fragment order
  const int tid = threadIdx.x, g = blockIdx.x;

  for (int i = tid; i < 4096; i += 256)
    ((u16x8*)ldsWh)[i] = ((const u16x8*)(whf + (long long)g * 32768))[i];
  for (int i = tid; i < 2048; i += 256)
    ((u16x8*)ldsWx)[i] = ((const u16x8*)(wxf + (long long)g * 16384))[i];
  __syncthreads();

  const int wave = tid >> 6, lane = tid & 63;
  const int c = lane & 15, q = lane >> 4;
  const int rowA = wave * 16 + c;   // A-operand batch row
  const int kofs = q * 8;
  const int j = 8 * g + (c & 7);    // hidden index owned (lanes c<8)
  const float bias0 = bias[(c >> 3) * H_ + j];        // i (c<8) / f (c>=8)
  const float bias1 = bias[(2 + (c >> 3)) * H_ + j];  // g / o
  const int rowD = wave * 16 + q * 4;
  f32x4 cst = {0.f, 0.f, 0.f, 0.f};

  const unsigned short* xrow = x16 + (long long)rowA * (S_ * I_) + kofs;
  const unsigned short* hrowA = hbuf + rowA * H_ + kofs;

  for (int t = 0; t < S_; ++t) {
    f32x4 a0 = {bias0, bias0, bias0, bias0};
    f32x4 a1 = {bias1, bias1, bias1, bias1};

    // ---- x-part: independent of h_t, overlaps barrier wait ----
    const unsigned short* xp = xrow + t * I_;
#pragma unroll
    for (int kc = 0; kc < 16; ++kc) {
      bf16x8 av = *(const bf16x8*)(xp + kc * 32);
      bf16x8 b0 = *(const bf16x8*)(ldsWx + kc * 512 + lane * 8);
      bf16x8 b1 = *(const bf16x8*)(ldsWx + (16 + kc) * 512 + lane * 8);
      a0 = __builtin_amdgcn_mfma_f32_16x16x32_bf16(av, b0, a0, 0, 0, 0);
      a1 = __builtin_amdgcn_mfma_f32_16x16x32_bf16(av, b1, a1, 0, 0, 0);
    }

    // ---- wait until all 128 producers published h_t (flag[g] == t means
    //      block g finished step t-1). Relaxed agent loads: L2-bypass,
    //      NO buffer_inv. Wave 0 polls, others park at the barrier. ----
    if (t > 0) {
      if (tid < 64) {
        const unsigned tgt = (unsigned)t;
        for (;;) {
          unsigned f0 = __hip_atomic_load(flags + tid, __ATOMIC_RELAXED,
                                          __HIP_MEMORY_SCOPE_AGENT);
          unsigned f1 = __hip_atomic_load(flags + 64 + tid, __ATOMIC_RELAXED,
                                          __HIP_MEMORY_SCOPE_AGENT);
          if (__all(f0 >= tgt && f1 >= tgt)) break;
        }
      }
      __syncthreads();
    }

    // ---- h-part: bulk-issue all 64 u64 L2-bypass loads, then MFMA ----
    const unsigned long long* hq =
        (const unsigned long long*)(hrowA + (t & 1) * (B_ * H_));
    unsigned long long hlo[32], hhi[32];
#pragma unroll
    for (int kc = 0; kc < 32; ++kc) {
      hlo[kc] = __hip_atomic_load(hq + kc * 8, __ATOMIC_RELAXED,
                                  __HIP_MEMORY_SCOPE_AGENT);
      hhi[kc] = __hip_atomic_load(hq + kc * 8 + 1, __ATOMIC_RELAXED,
                                  __HIP_MEMORY_SCOPE_AGENT);
    }
#pragma unroll
    for (int kc = 0; kc < 32; ++kc) {
      union { unsigned long long qw[2]; bf16x8 v; } u;
      u.qw[0] = hlo[kc]; u.qw[1] = hhi[kc];
      bf16x8 av = u.v;
      bf16x8 b0 = *(const bf16x8*)(ldsWh + kc * 512 + lane * 8);
      bf16x8 b1 = *(const bf16x8*)(ldsWh + (32 + kc) * 512 + lane * 8);
      a0 = __builtin_amdgcn_mfma_f32_16x16x32_bf16(av, b0, a0, 0, 0, 0);
      a1 = __builtin_amdgcn_mfma_f32_16x16x32_bf16(av, b1, a1, 0, 0, 0);
    }

    // ---- elementwise LSTM update (lane c pairs with lane c+8) ----
    f32x4 h4;
#pragma unroll
    for (int r = 0; r < 4; ++r) {
      float fg = __shfl_xor(a0[r], 8, 64);  // f at lanes c<8
      float og = __shfl_xor(a1[r], 8, 64);  // o at lanes c<8
      float iv = sigf(a0[r]);
      float fv = sigf(fg);
      float gv = tanh_(a1[r]);
      float ov = sigf(og);
      float cv = fv * cst[r] + iv * gv;
      cst[r] = cv;
      h4[r] = ov * tanh_(cv);
    }
    if (c < 8) {
      unsigned short* hw = hbuf + ((t + 1) & 1) * (B_ * H_);
#pragma unroll
      for (int r = 0; r < 4; ++r) {
        int b = rowD + r;
        unsigned short hb = f2b(h4[r]);
        unsigned pv = (unsigned)__shfl_xor((int)hb, 1, 64) & 0xffffu;
        if ((c & 1) == 0) {
          // paired u32 bf16 store, L2-bypass (agent relaxed)
          __hip_atomic_store((unsigned*)(hw + b * H_ + j),
                             ((unsigned)hb) | (pv << 16), __ATOMIC_RELAXED,
                             __HIP_MEMORY_SCOPE_AGENT);
        }
        out[((long long)b * S_ + t) * H_ + j] = h4[r];
      }
      if (t == S_ - 1) {
#pragma unroll
        for (int r = 0; r < 4; ++r) {
          int b = rowD + r;
          out[OFF_H + b * H_ + j] = h4[r];
          out[OFF_C + b * H_ + j] = cst[r];
        }
      }
    }

    // ---- publish: __syncthreads drains vmcnt(0) per wave (valid agent
    //      release since h stores bypassed L2), then one flag store. ----
    __syncthreads();
    if (tid == 0)
      __hip_atomic_store(flags + g, (unsigned)(t + 1), __ATOMIC_RELAXED,
                         __HIP_MEMORY_SCOPE_AGENT);
  }
}

extern "C" void kernel_launch(void* const* d_in, const int* in_sizes, int n_in,
                              void* d_out, int out_size, void* d_ws, size_t ws_size,
                              hipStream_t stream) {
  const float* x = (const float*)d_in[0];
  const float* Wx = (const float*)d_in[1];
  const float* Wh = (const float*)d_in[2];
  const float* bias = (const float*)d_in[3];
  float* out = (float*)d_out;
  char* ws = (char*)d_ws;

  // ws layout (bytes):
  //   [0,512)          flags[128] (u32 epoch per producer block)
  //   [1024, 263168)   h double buffer, bf16 [2][64][1024]
  //   [263168, ..)     x16 bf16 (33.5 MB)
  //   [33817600, ..)   wxf fragment-ordered W_x bf16 (4 MB)
  //   [38011904, ..)   whf fragment-ordered W_h bf16 (8 MB)   total ~46.4 MB
  unsigned* flags = (unsigned*)ws;
  unsigned short* hbuf = (unsigned short*)(ws + 1024);
  unsigned short* x16 = (unsigned short*)(ws + 263168);
  unsigned short* wxf = (unsigned short*)(ws + 33817600);
  unsigned short* whf = (unsigned short*)(ws + 38011904);

  hipMemsetAsync(ws, 0, 263168, stream);  // zero flags + h0
  hipLaunchKernelGGL(k_cvt_x, dim3(8192), dim3(256), 0, stream, x, x16);
  hipLaunchKernelGGL(k_wx, dim3(1024), dim3(256), 0, stream, Wx, wxf);
  hipLaunchKernelGGL(k_wh, dim3(2048), dim3(256), 0, stream, Wh, whf);
  hipLaunchKernelGGL(k_scan, dim3(NBLK), dim3(256), 0, stream, x16, wxf, whf, bias,
                     hbuf, flags, out);
  (void)in_sizes; (void)n_in; (void)out_size; (void)ws_size;
}